// Round 12
// baseline (379.625 us; speedup 1.0000x reference)
//
#include <hip/hip_runtime.h>
#include <hip/hip_bf16.h>
#include <cstdint>
#include <cstddef>

typedef __attribute__((ext_vector_type(8))) short  s8v;
typedef __attribute__((ext_vector_type(4))) short  s4v;
typedef __attribute__((ext_vector_type(8))) __bf16 b8v;
typedef __attribute__((ext_vector_type(4))) float  f32x4;
typedef __attribute__((ext_vector_type(4))) unsigned u32x4;

#define SC2Q 0.0450843293f   /* E^-0.5 * log2(e) */

__device__ __forceinline__ short f2bf(float f){
  unsigned u = __builtin_bit_cast(unsigned, f);
  unsigned r = (u + 0x7fffu + ((u >> 16) & 1u)) >> 16;   // RNE
  return (short)(unsigned short)r;
}
__device__ __forceinline__ float bf2f(short s){
  return __builtin_bit_cast(float, ((unsigned)(unsigned short)s) << 16);
}

__device__ __forceinline__ f32x4 mfma16(s8v a, s8v b, f32x4 c){
  return __builtin_amdgcn_mfma_f32_16x16x32_bf16(
      __builtin_bit_cast(b8v, a), __builtin_bit_cast(b8v, b), c, 0, 0, 0);
}

__device__ __forceinline__ unsigned cvtpk(float a, float b){
  unsigned w;
  asm("v_cvt_pk_bf16_f32 %0, %1, %2" : "=v"(w) : "v"(a), "v"(b));
  return w;
}

// ---------------- LayerNorm over E=1024 -> bf16 ----------------
__global__ __launch_bounds__(256)
void ln_k(const float* __restrict__ x, const float* __restrict__ g,
          const float* __restrict__ b, short* __restrict__ out)
{
  const int row = blockIdx.x, tid = threadIdx.x;
  const float4 v = ((const float4*)(x + (size_t)row*1024))[tid];
  float s  = v.x+v.y+v.z+v.w;
  float s2 = v.x*v.x+v.y*v.y+v.z*v.z+v.w*v.w;
  #pragma unroll
  for (int off=32; off; off>>=1){ s += __shfl_down(s, off); s2 += __shfl_down(s2, off); }
  __shared__ float red[8];
  const int wave = tid>>6, lane = tid&63;
  if (lane==0){ red[wave]=s; red[4+wave]=s2; }
  __syncthreads();
  s  = red[0]+red[1]+red[2]+red[3];
  s2 = red[4]+red[5]+red[6]+red[7];
  const float mean = s*(1.f/1024.f);
  const float rstd = rsqrtf(s2*(1.f/1024.f) - mean*mean + 1e-5f);
  const float4 gv = ((const float4*)g)[tid];
  const float4 bv = ((const float4*)b)[tid];
  s4v o;
  o[0] = f2bf((v.x-mean)*rstd*gv.x + bv.x);
  o[1] = f2bf((v.y-mean)*rstd*gv.y + bv.y);
  o[2] = f2bf((v.z-mean)*rstd*gv.z + bv.z);
  o[3] = f2bf((v.w-mean)*rstd*gv.w + bv.w);
  *(s4v*)(out + (size_t)row*1024 + tid*4) = o;
}

// ---------------- f32 -> bf16 cast (4 elems/thread) ----------------
__global__ __launch_bounds__(256)
void cast_k(const float* __restrict__ in, short* __restrict__ out)
{
  const int i = blockIdx.x*256 + threadIdx.x;
  const float4 v = ((const float4*)in)[i];
  s4v o; o[0]=f2bf(v.x); o[1]=f2bf(v.y); o[2]=f2bf(v.z); o[3]=f2bf(v.w);
  ((s4v*)out)[i] = o;
}

// ---- mask int -> additive f32 bias (0 / -1.5e9), both masks in one launch ----
__global__ __launch_bounds__(256)
void mkb_k(const int* __restrict__ xm, const int* __restrict__ cm,
           float* __restrict__ mbS, float* __restrict__ mbC)
{
  const int i = blockIdx.x*256 + threadIdx.x;
  mbS[i] = xm[i] ? 0.f : -1.5e9f;
  mbC[i] = cm[i] ? 0.f : -1.5e9f;
}

// ------- transpose+cast: in (gridDim.z, E2, D2) f32 -> out (gridDim.z*D2, E2) bf16 -------
__global__ __launch_bounds__(256)
void tcast_k(const float* __restrict__ in, short* __restrict__ out, int E2, int D2)
{
  __shared__ float t[32][33];
  const int h  = blockIdx.z;
  const int e0 = blockIdx.x*32, d0 = blockIdx.y*32;
  const int tx = threadIdx.x & 31, ty = threadIdx.x >> 5;
  const float* ip = in + (size_t)h*E2*D2;
  #pragma unroll
  for (int r = ty; r < 32; r += 8)
    t[r][tx] = ip[(size_t)(e0+r)*D2 + d0 + tx];
  __syncthreads();
  short* op = out + (size_t)h*D2*E2;
  #pragma unroll
  for (int r = ty; r < 32; r += 8)
    op[(size_t)(d0+r)*E2 + e0 + tx] = f2bf(t[tx][r]);
}

// ------- bf16 transpose+PERMUTE: V (b,s,h,d) -> Vp[b*H+h][d][s'] where within each
// 64-block s' = ks*32 + hi*8 + e  <->  s = ks*32 + 16*(e>>2) + 4*hi + (e&3)
__global__ __launch_bounds__(256)
void vtrans_k(const short* __restrict__ V, int ldv, short* __restrict__ Vt, int S, int H)
{
  __shared__ short t[32][34];
  const int bh = blockIdx.z;
  const int b = bh / H, h = bh % H;
  const int s0 = blockIdx.x*32, d0 = blockIdx.y*32;
  const int tx = threadIdx.x & 31, ty = threadIdx.x >> 5;
  const short* ip = V + (size_t)b*S*ldv + h*64;
  #pragma unroll
  for (int r = ty; r < 32; r += 8)
    t[r][tx] = ip[(size_t)(s0+r)*ldv + d0 + tx];
  __syncthreads();
  const int s  = s0 + tx;
  const int ks = (s>>5)&1, bb = (tx>>4)&1, hh = (tx>>2)&3, rr = tx&3;
  const int cp = (s & ~63) + ks*32 + hh*8 + bb*4 + rr;
  short* op = Vt + ((size_t)bh*64 + d0)*S;
  #pragma unroll
  for (int r = ty; r < 32; r += 8)
    op[(size_t)r*S + cp] = t[tx][r];
}

// ---- split-K=4 reduce: out = sum(bf16 partials) + bias + resid (f32) ----
__global__ __launch_bounds__(256)
void red4_k(const short* __restrict__ p, const float* __restrict__ bias,
            const float* __restrict__ resid, float* __restrict__ out)
{
  const int i = blockIdx.x*256 + threadIdx.x;
  float4 o = ((const float4*)resid)[i];
  const float4 bv = ((const float4*)bias)[i & 255];
  o.x += bv.x; o.y += bv.y; o.z += bv.z; o.w += bv.w;
  #pragma unroll
  for (int z=0; z<4; z++){
    const s4v v = ((const s4v*)(p + (size_t)z*4194304))[i];
    o.x += bf2f(v[0]); o.y += bf2f(v[1]); o.z += bf2f(v[2]); o.w += bf2f(v[3]);
  }
  ((float4*)out)[i] = o;
}

// ------- 2-phase bf16 GEMM (narrow-N path). SCQ: 0=none, 2=scale all cols -------
template<int BN, int BIAS, int RELU, int RESID, int WF32, int SCQ>
__global__ __launch_bounds__(256, 2)
void gemm_bt(const short* __restrict__ A, const short* __restrict__ Bt,
             const float* __restrict__ bias, const float* __restrict__ resid,
             short* __restrict__ Cb, float* __restrict__ Cf,
             int M, int N, int K)
{
  __shared__ short lds[3][128*32 + BN*32];
  const int nwg = gridDim.x * gridDim.y;
  int id = blockIdx.y * gridDim.x + blockIdx.x;
  id = (id & 7) * (nwg >> 3) + (id >> 3);
  const int bx = id % gridDim.x, by = id / gridDim.x;
  const int m0 = by*128, n0 = bx*BN;

  const int tid  = threadIdx.x;
  const int wave = tid>>6, lane = tid&63;
  const int lo = lane&15, hi = lane>>4;
  const int wm = wave>>1, wn = wave&1;

  constexpr int NJ = BN/32;
  constexpr int BC = BN>>6;
  f32x4 acc[4][NJ] = {};
  const int NK = K >> 5;

  auto stage = [&](int buf, int kt){
    const short* Ag = A  + (size_t)m0*K + kt*32;
    const short* Bg = Bt + (size_t)n0*K + kt*32;
    #pragma unroll
    for (int c=0;c<2;c++){
      const int q = (wave*2+c)*64 + lane;
      const int r = q>>2, cc = q&3;
      __builtin_amdgcn_global_load_lds(
        (const __attribute__((address_space(1))) void*)(Ag + (size_t)r*K + cc*8),
        (__attribute__((address_space(3))) void*)(&lds[buf][(wave*2+c)*512]),
        16, 0, 0);
    }
    #pragma unroll
    for (int c=0;c<BC;c++){
      const int q = (wave*BC+c)*64 + lane;
      const int r = q>>2, cc = q&3;
      __builtin_amdgcn_global_load_lds(
        (const __attribute__((address_space(1))) void*)(Bg + (size_t)r*K + cc*8),
        (__attribute__((address_space(3))) void*)(&lds[buf][4096 + (wave*BC+c)*512]),
        16, 0, 0);
    }
  };

  stage(0, 0);
  if (NK > 1) stage(1, 1);

  for (int kt=0; kt<NK; kt++){
    if (kt+1 < NK){
      if constexpr (BN==128) asm volatile("s_waitcnt vmcnt(4)" ::: "memory");
      else                   asm volatile("s_waitcnt vmcnt(3)" ::: "memory");
    } else {
      asm volatile("s_waitcnt vmcnt(0)" ::: "memory");
    }
    __builtin_amdgcn_s_barrier();
    __builtin_amdgcn_sched_barrier(0);
    if (kt+2 < NK) stage((kt+2)%3, kt+2);

    const short* la = &lds[kt%3][0];
    const short* lb = &lds[kt%3][4096];
    s8v af[4], bfr[NJ];
    #pragma unroll
    for (int i=0;i<4;i++)
      af[i] = *(const s8v*)(la + (wm*64 + i*16 + lo)*32 + hi*8);
    #pragma unroll
    for (int j=0;j<NJ;j++)
      bfr[j] = *(const s8v*)(lb + (wn*(BN/2) + j*16 + lo)*32 + hi*8);
    #pragma unroll
    for (int i=0;i<4;i++)
      #pragma unroll
      for (int j=0;j<NJ;j++)
        acc[i][j] = mfma16(af[i], bfr[j], acc[i][j]);
  }

  #pragma unroll
  for (int i=0;i<4;i++){
    const int row = m0 + wm*64 + i*16 + hi*4;
    #pragma unroll
    for (int j=0;j<NJ;j++){
      const int col = n0 + wn*(BN/2) + j*16 + lo;
      const float bv = BIAS ? bias[col] : 0.0f;
      #pragma unroll
      for (int r=0;r<4;r++){
        float v = acc[i][j][r] + bv;
        if constexpr (SCQ==2) v *= SC2Q;
        if (RELU) v = fmaxf(v, 0.0f);
        const size_t idx = (size_t)(row + r)*N + col;
        if (RESID) v += resid[idx];
        if (WF32) Cf[idx] = v; else Cb[idx] = f2bf(v);
      }
    }
  }
}

// ------- m201-geometry bf16 GEMM: 256x256, BK=64, 8 waves, per-wave 128x64. -------
template<int BIAS, int RELU, int RESID, int WF32, int SCQ>
__global__ __launch_bounds__(512, 1)
void gemm256(const short* __restrict__ A, int lda,
             const short* __restrict__ Bt, int ldb,
             const float* __restrict__ bias, const float* __restrict__ resid,
             short* __restrict__ Cb, float* __restrict__ Cf,
             int M, int N, int K)
{
  __shared__ short lds[2][32768];
  const int nwg = gridDim.x * gridDim.y;
  int id = blockIdx.y * gridDim.x + blockIdx.x;
  id = (id & 7) * (nwg >> 3) + (id >> 3);
  const int bx = id % gridDim.x, by = id / gridDim.x;
  const int m0 = by*256, n0 = bx*256;
  A  += (size_t)blockIdx.z * K;
  Bt += (size_t)blockIdx.z * K;
  const size_t cofs = (size_t)blockIdx.z * M * N;

  const int tid = threadIdx.x;
  const int lane = tid&63, wave = tid>>6;
  const int lo = lane&15, hi = lane>>4;
  const int wr = wave>>2, wc = wave&3;

  f32x4 acc[8][4] = {};
  const int NT = K >> 6;

  auto stageA = [&](int buf, int kt, int part){
    const short* Ag = A + (size_t)m0*lda + kt*64;
    const int q = part*512 + tid;
    const int r = q>>3, c = q&7;
    __builtin_amdgcn_global_load_lds(
      (const __attribute__((address_space(1))) void*)(Ag + (size_t)r*lda + ((c^(r&7))*8)),
      (__attribute__((address_space(3))) void*)(&lds[buf][q*8]), 16, 0, 0);
  };
  auto stageB = [&](int buf, int kt, int part){
    const short* Bg = Bt + (size_t)n0*ldb + kt*64;
    const int q = part*512 + tid;
    const int r = q>>3, c = q&7;
    __builtin_amdgcn_global_load_lds(
      (const __attribute__((address_space(1))) void*)(Bg + (size_t)r*ldb + ((c^(r&7))*8)),
      (__attribute__((address_space(3))) void*)(&lds[buf][16384 + q*8]), 16, 0, 0);
  };

  #pragma unroll
  for (int p=0;p<4;p++){ stageA(0,0,p); stageB(0,0,p); }
  __syncthreads();

  for (int t=0; t<NT; t++){
    const int cur = t&1;
    const short* la = &lds[cur][0];
    const short* lb = &lds[cur][16384];
    const bool pf = (t+1 < NT);
    #pragma unroll
    for (int ks=0; ks<2; ks++){
      s8v bf[4];
      #pragma unroll
      for (int j=0;j<4;j++){
        const int r = wc*64 + j*16 + lo;
        bf[j] = *(const s8v*)(lb + r*64 + (((ks*4+hi)^(r&7))*8));
      }
      #pragma unroll
      for (int mh=0; mh<2; mh++){
        s8v af[4];
        #pragma unroll
        for (int i=0;i<4;i++){
          const int r = wr*128 + mh*64 + i*16 + lo;
          af[i] = *(const s8v*)(la + r*64 + (((ks*4+hi)^(r&7))*8));
        }
        if (pf && ks==0){
          stageA(cur^1, t+1, mh*2);   stageB(cur^1, t+1, mh*2);
          stageA(cur^1, t+1, mh*2+1); stageB(cur^1, t+1, mh*2+1);
        }
        __builtin_amdgcn_s_setprio(1);
        #pragma unroll
        for (int i=0;i<4;i++)
          #pragma unroll
          for (int j=0;j<4;j++)
            acc[mh*4+i][j] = mfma16(af[i], bf[j], acc[mh*4+i][j]);
        __builtin_amdgcn_s_setprio(0);
      }
    }
    __syncthreads();
  }

  #pragma unroll
  for (int I=0;I<8;I++){
    const int row = m0 + wr*128 + I*16 + hi*4;
    #pragma unroll
    for (int j=0;j<4;j++){
      const int col = n0 + wc*64 + j*16 + lo;
      const float bv = BIAS ? bias[col] : 0.0f;
      #pragma unroll
      for (int r=0;r<4;r++){
        float v = acc[I][j][r] + bv;
        if constexpr (SCQ==1) { if (col < 1024) v *= SC2Q; }
        if (RELU) v = fmaxf(v, 0.0f);
        const size_t idx = cofs + (size_t)(row + r)*N + col;
        if (RESID) v += resid[idx];
        if (WF32) Cf[idx] = v; else Cb[idx] = f2bf(v);
      }
    }
  }
}

// ---- flash attention v8: T15 pipeline (QK(t+1) ahead of PV(t)) + T3/T4 3-buffer
// counted-vmcnt ring. Hoisted addressing, lrow-via-ones-MFMA, pre-scaled Q,
// additive mask bias, defer-max, b128 V frags (permuted Vp).
template<int CAUSAL>
__global__ __launch_bounds__(256, 3)
void attn_k(const short* __restrict__ Q, int ldq,
            const short* __restrict__ K, int ldk,
            const short* __restrict__ Vt, int ldvt,   // Vp[b*H+h][d][s'] permuted
            const float* __restrict__ mbias,
            short* __restrict__ O, int ldo,
            int H, int Tq, int Sk)
{
  __shared__ short kls[3][4096];
  __shared__ short vls[3][4096];
  const int bh = blockIdx.x;
  const int b = bh / H, h = bh % H;
  const int tid = threadIdx.x;
  const int wave = tid>>6, lane = tid&63;
  const int lo = lane&15, hi = lane>>4;
  const int t0 = blockIdx.y*64 + wave*16;

  const short* Qb  = Q + (size_t)(b*Tq)*ldq + h*64;
  const short* Kb  = K + (size_t)(b*Sk)*ldk + h*64;
  const short* Vtb = Vt + (size_t)bh*64*ldvt;

  const short* qp = Qb + (size_t)(t0+lo)*ldq + hi*8;
  const s8v qa0 = *(const s8v*)(qp);
  const s8v qa1 = *(const s8v*)(qp + 32);

  float mrow = -INFINITY;
  f32x4 oacc[4] = {};
  f32x4 oaccL = {};
  const int trow = t0 + lo;
  const int nblk = CAUSAL ? (blockIdx.y + 1) : (Sk>>6);
  const int x8 = lo & 7;

  const s8v onesv = {(short)0x3F80,(short)0x3F80,(short)0x3F80,(short)0x3F80,
                     (short)0x3F80,(short)0x3F80,(short)0x3F80,(short)0x3F80};

  // staging source pointers
  const int q0 = tid, q1 = 256 + tid;
  const int r0 = q0>>3, cs0 = ((q0&7) ^ (r0&7))*8;
  const int r1 = q1>>3, cs1 = ((q1&7) ^ (r1&7))*8;
  const short* kS0 = Kb + (size_t)r0*ldk + cs0;
  const short* kS1 = Kb + (size_t)r1*ldk + cs1;
  const short* vS0 = Vtb + (size_t)r0*ldvt + cs0;
  const short* vS1 = Vtb + (size_t)r1*ldvt + cs1;
  const size_t kAdv = (size_t)64*ldk;

  auto stage = [&](int b3){
    __builtin_amdgcn_global_load_lds(
      (const __attribute__((address_space(1))) void*)kS0,
      (__attribute__((address_space(3))) void*)(&kls[b3][wave*512]), 16, 0, 0);
    __builtin_amdgcn_global_load_lds(
      (const __attribute__((address_space(1))) void*)kS1,
      (__attribute__((address_space(3))) void*)(&kls[b3][2048 + wave*512]), 16, 0, 0);
    __builtin_amdgcn_global_load_lds(
      (const __attribute__((address_space(1))) void*)vS0,
      (__attribute__((address_space(3))) void*)(&vls[b3][wave*512]), 16, 0, 0);
    __builtin_amdgcn_global_load_lds(
      (const __attribute__((address_space(1))) void*)vS1,
      (__attribute__((address_space(3))) void*)(&vls[b3][2048 + wave*512]), 16, 0, 0);
    kS0 += kAdv; kS1 += kAdv; vS0 += 64; vS1 += 64;
  };

  const char* klsB = (const char*)kls;
  const char* vlsB = (const char*)vls;
  const int A0 = lo*128 + ((hi     ^ x8)*16);
  const int A1 = lo*128 + (((4+hi) ^ x8)*16);
  const char* mbp = (const char*)(mbias + (size_t)b*Sk) + hi*16;

  auto qk = [&](int b3, f32x4 (&sg)[4]){
    const char* ka0 = klsB + b3*8192 + A0;
    const char* ka1 = klsB + b3*8192 + A1;
    s8v kf0[4], kf1[4];
    #pragma unroll
    for (int g=0; g<4; g++){
      kf0[g] = *(const s8v*)(ka0 + g*2048);
      kf1[g] = *(const s8v*)(ka1 + g*2048);
    }
    const f32x4 z = {};
    __builtin_amdgcn_s_setprio(1);
    #pragma unroll
    for (int g=0; g<4; g++){
      sg[g] = mfma16(kf0[g], qa0, z);
      sg[g] = mfma16(kf1[g], qa1, sg[g]);
    }
    __builtin_amdgcn_s_setprio(0);
  };

  f32x4 sgA[4], sgB[4];
  int rB = 0, wB = 2;          // read buffer for tile t; write buffer for tile t+2
  auto nxt3 = [](int v){ return v==2 ? 0 : v+1; };

  // iteration body: softmax(t) on In, prefetch/stage, QK(t+1)->Out, PV(t)
  auto iter = [&](int t, f32x4 (&In)[4], f32x4 (&Out)[4]){
    __builtin_amdgcn_s_barrier();                       // B1: PV(t-1) reads done
    if (t+2 < nblk){ stage(wB); wB = nxt3(wB); }

    // ---- softmax(t) ----
    float p[4][4];
    #pragma unroll
    for (int g=0; g<4; g++){
      const f32x4 mv = *(const f32x4*)(mbp + g*64);
      #pragma unroll
      for (int r=0; r<4; r++)
        p[g][r] = In[g][r] + mv[r];
    }
    mbp += 256;
    if (CAUSAL && t == nblk-1){
      const int s0 = t*64;
      #pragma unroll
      for (int g=0; g<4; g++)
        #pragma unroll
        for (int r=0; r<4; r++){
          const int sidx = s0 + g*16 + 4*hi + r;
          if (sidx > trow) p[g][r] = -1.5e9f;
        }
    }
    float bmax;
    {
      const float m0_ = fmaxf(fmaxf(p[0][0],p[0][1]),p[0][2]);
      const float m1_ = fmaxf(fmaxf(p[0][3],p[1][0]),p[1][1]);
      const float m2_ = fmaxf(fmaxf(p[1][2],p[1][3]),p[2][0]);
      const float m3_ = fmaxf(fmaxf(p[2][1],p[2][2]),p[2][3]);
      const float m4_ = fmaxf(fmaxf(p[3][0],p[3][1]),p[3][2]);
      bmax = fmaxf(fmaxf(fmaxf(m0_,m1_),m2_), fmaxf(fmaxf(m3_,m4_),p[3][3]));
    }
    bmax = fmaxf(bmax, __shfl_xor(bmax, 16));
    bmax = fmaxf(bmax, __shfl_xor(bmax, 32));
    if (!__all(bmax <= mrow + 8.0f)){
      const float mn  = fmaxf(mrow, bmax);
      const float fac = exp2f(mrow - mn);
      mrow = mn;
      #pragma unroll
      for (int f=0; f<4; f++)
        #pragma unroll
        for (int r=0; r<4; r++)
          oacc[f][r] *= fac;
      #pragma unroll
      for (int r=0; r<4; r++) oaccL[r] *= fac;
    }
    #pragma unroll
    for (int g=0; g<4; g++)
      #pragma unroll
      for (int r=0; r<4; r++)
        p[g][r] = exp2f(p[g][r] - mrow);

    u32x4 pw0, pw1;
    pw0[0] = cvtpk(p[0][0], p[0][1]);
    pw0[1] = cvtpk(p[0][2], p[0][3]);
    pw0[2] = cvtpk(p[1][0], p[1][1]);
    pw0[3] = cvtpk(p[1][2], p[1][3]);
    pw1[0] = cvtpk(p[2][0], p[2][1]);
    pw1[1] = cvtpk(p[2][2], p[2][3]);
    pw1[2] = cvtpk(p[3][0], p[3][1]);
    pw1[3] = cvtpk(p[3][2], p[3][3]);
    const s8v pb0 = __builtin_bit_cast(s8v, pw0);
    const s8v pb1 = __builtin_bit_cast(s8v, pw1);

    // ---- tile t+1 readiness (counted, per-wave) + cross-wave barrier ----
    if (t+1 < nblk){
      if (t+2 < nblk) asm volatile("s_waitcnt vmcnt(4)" ::: "memory");
      else            asm volatile("s_waitcnt vmcnt(0)" ::: "memory");
    }
    __builtin_amdgcn_s_barrier();                       // B2
    if (t+1 < nblk) qk(nxt3(rB), Out);                  // MFMA ahead of PV

    // ---- PV(t) ----
    const char* va0 = vlsB + rB*8192 + A0;
    const char* va1 = vlsB + rB*8192 + A1;
    __builtin_amdgcn_s_setprio(1);
    #pragma unroll
    for (int f=0; f<4; f++){
      const s8v av0 = *(const s8v*)(va0 + f*2048);
      const s8v av1 = *(const s8v*)(va1 + f*2048);
      oacc[f] = mfma16(av0, pb0, oacc[f]);
      oacc[f] = mfma16(av1, pb1, oacc[f]);
    }
    oaccL = mfma16(onesv, pb0, oaccL);
    oaccL = mfma16(onesv, pb1, oaccL);
    __builtin_amdgcn_s_setprio(0);
    rB = nxt3(rB);
  };

  // prologue: tiles 0,1 in flight; QK(0)
  stage(0); stage(1);
  asm volatile("s_waitcnt vmcnt(4)" ::: "memory");
  __builtin_amdgcn_s_barrier();
  qk(0, sgA);

  int t = 0;
  while (t < nblk){
    iter(t, sgA, sgB); t++;
    if (t >= nblk) break;
    iter(t, sgB, sgA); t++;
  }

  const float inv = 1.0f / oaccL[0];
  short* Ob = O + (size_t)(b*Tq)*ldo + h*64 + (size_t)(t0+lo)*ldo + 4*hi;
  #pragma unroll
  for (int f=0; f<4; f++){
    s4v o;
    #pragma unroll
    for (int r=0; r<4; r++) o[r] = f2bf(oacc[f][r]*inv);
    *(s4v*)(Ob + f*16) = o;
  }
}

// =============================== host ===============================
extern "C" void kernel_launch(void* const* d_in, const int* in_sizes, int n_in,
                              void* d_out, int out_size, void* d_ws, size_t ws_size,
                              hipStream_t stream)
{
  (void)in_sizes; (void)n_in; (void)out_size; (void)ws_size;
  const float* x    = (const float*)d_in[0];
  const int*   xm   = (const int*)  d_in[1];
  const float* ca   = (const float*)d_in[2];
  const int*   cam  = (const int*)  d_in[3];
  const float* Wq_s = (const float*)d_in[4];
  const float* Wk_s = (const float*)d_in[5];
  const float* Wv_s = (const float*)d_in[6];
  const float* Wo_s = (const float*)d_in[7];
  const float* bo_s = (const float*)d_in[8];
  const float* Wq_c = (const float*)d_in[9];
  const float* Wk_c = (const float*)d_in[10];
  const float* Wv_c = (const float*)d_in[11];
  const float* Wo_c = (const float*)d_in[12];
  const float* bo_c = (const float*)d_in[13];
  const float* ln1g = (const float*)d_in[14];
  const float* ln1b = (const float*)d_in[15];
  const float* ln2g = (const float*)d_in[16];
  const float* ln2b = (const float*)d_in[17];
  const float* ln3g = (const float*)d_in[18];
  const float* ln3b = (const float*)d_in[19];
  const float* W1   = (const float*)d_in[20];
  const float* b1   = (const float*)d_in[21];
  const float* W2   = (const float*)d_in[22];
  const float* b2   = (const float*)d_in[23];
  float* out = (float*)d_out;

  char* ws = (char*)d_ws;
  size_t off = 0;
  auto alloc = [&](size_t bytes)->void*{
    void* p = ws + off; off += (bytes + 255) & ~(size_t)255; return p; };

  short* w_qkv_s = (short*)alloc((size_t)3072*1024*2);
  short* w_o_s   = (short*)alloc((size_t)1024*1024*2);
  short* w_q_c   = (short*)alloc((size_t)1024*1024*2);
  short* w_kv_c  = (short*)alloc((size_t)2048*1024*2);
  short* w_o_c   = (short*)alloc((size_t)1024*1024*2);
  short* w_1     = (short*)alloc((size_t)4096*1024*2);
  short* w_2     = (short*)alloc((size_t)1024*4096*2);
  short* xn      = (short*)alloc((size_t)4096*1024*2);
  short* cab     = (short*)alloc((size_t)4096*1024*2);
  short* qkv     = (short*)alloc((size_t)4096*3072*2);
  short* attno   = (short*)alloc((size_t)4096*1024*2);
  float* xres    = (float*)alloc((size_t)4096*1024*4);
  short* hffn    = (short*)alloc((size_t)4096*4096*2);
  float* pA      = (float*)alloc((size_t)4096*1024*4);
  float* pB      = (float*)alloc((size_t)4096*1024*4);
  float* mbS     = (float*)alloc((size_t)4096*4);
  float* mbC     = (float*)alloc((size_t)4096*4);
  short* pP      = (short*)pA;
  short* kvbuf   = qkv + (size_t)4096*1024;
  short* vt_s    = hffn;
  short* vt_c    = hffn + (size_t)4*1024*1024;
  (void)pB;

  tcast_k<<<dim3(32,  2,16),256,0,stream>>>(Wq_s, w_qkv_s,           1024,   64);
  tcast_k<<<dim3(32,  2,16),256,0,stream>>>(Wk_s, w_qkv_s+1024*1024, 1024,   64);
  tcast_k<<<dim3(32,  2,16),256,0,stream>>>(Wv_s, w_qkv_s+2048*1024, 1024,   64);
  tcast_k<<<dim3(32, 32, 1),256,0,stream>>>(Wo_s, w_o_s,             1024, 1024);
  tcast_k<<<dim3(32,  2,16),256,0,stream>>>(Wq_c, w_q_c,             1024,   64);
  tcast_k<<<dim3(32,  2,16),256,0,stream>>>(Wk_c, w_kv_c,            1024,   64);
  tcast_k<<<dim3(32,  2,16),256,0,stream>>>(Wv_c, w_kv_c+1024*1024,  1024,   64);
  tcast_k<<<dim3(32, 32, 1),256,0,stream>>>(Wo_c, w_o_c,             1024, 1024);
  tcast_k<<<dim3(32,128, 1),256,0,stream>>>(W1,   w_1,               1024, 4096);
  tcast_k<<<dim3(128,32, 1),256,0,stream>>>(W2,   w_2,               4096, 1024);
  cast_k<<<4096,256,0,stream>>>(ca, cab);
  mkb_k<<<16,256,0,stream>>>(xm, cam, mbS, mbC);

  // --- self attention ---
  ln_k<<<4096,256,0,stream>>>(x, ln1g, ln1b, xn);
  gemm256<0,0,0,0,1><<<dim3(12,16),512,0,stream>>>(xn, 1024, w_qkv_s, 1024,
                                                   nullptr, nullptr, qkv, nullptr,
                                                   4096, 3072, 1024);
  vtrans_k<<<dim3(32,2,64),256,0,stream>>>(qkv+2048, 3072, vt_s, 1024, 16);
  attn_k<1><<<dim3(64,16),256,0,stream>>>(qkv, 3072, qkv+1024, 3072, vt_s, 1024,
                                          mbS, attno, 1024, 16, 1024, 1024);
  gemm_bt<64,1,0,1,1,0><<<dim3(16,32),256,0,stream>>>(attno, w_o_s, bo_s, x,
                                                      nullptr, xres, 4096, 1024, 1024);

  // --- cross attention (K,V from raw ca) ---
  ln_k<<<4096,256,0,stream>>>(xres, ln2g, ln2b, xn);
  gemm_bt<64,0,0,0,0,2><<<dim3(16,32),256,0,stream>>>(xn, w_q_c, nullptr, nullptr,
                                                      qkv, nullptr, 4096, 1024, 1024);
  gemm256<0,0,0,0,0><<<dim3(8,16),512,0,stream>>>(cab, 1024, w_kv_c, 1024,
                                                  nullptr, nullptr, kvbuf, nullptr,
                                                  4096, 2048, 1024);
  vtrans_k<<<dim3(32,2,64),256,0,stream>>>(kvbuf+1024, 2048, vt_c, 1024, 16);
  attn_k<0><<<dim3(64,16),256,0,stream>>>(qkv, 1024, kvbuf, 2048, vt_c, 1024,
                                          mbC, attno, 1024, 16, 1024, 1024);
  gemm_bt<64,1,0,1,1,0><<<dim3(16,32),256,0,stream>>>(attno, w_o_c, bo_c, xres,
                                                      nullptr, xres, 4096, 1024, 1024);

  // --- FFN ---
  ln_k<<<4096,256,0,stream>>>(xres, ln3g, ln3b, xn);
  gemm256<1,1,0,0,0><<<dim3(16,16),512,0,stream>>>(xn, 1024, w_1, 1024,
                                                   b1, nullptr, hffn, nullptr,
                                                   4096, 4096, 1024);
  gemm256<0,0,0,0,0><<<dim3(4,16,4),512,0,stream>>>(hffn, 4096, w_2, 4096,
                                                    nullptr, nullptr, pP, nullptr,
                                                    4096, 1024, 1024);
  red4_k<<<4096,256,0,stream>>>(pP, b2, xres, out);
}

// Round 13
// 350.602 us; speedup vs baseline: 1.0828x; 1.0828x over previous
//
#include <hip/hip_runtime.h>
#include <hip/hip_bf16.h>
#include <cstdint>
#include <cstddef>

typedef __attribute__((ext_vector_type(8))) short  s8v;
typedef __attribute__((ext_vector_type(4))) short  s4v;
typedef __attribute__((ext_vector_type(8))) __bf16 b8v;
typedef __attribute__((ext_vector_type(4))) float  f32x4;
typedef __attribute__((ext_vector_type(4))) unsigned u32x4;

#define SC2Q 0.0450843293f   /* E^-0.5 * log2(e) */

__device__ __forceinline__ short f2bf(float f){
  unsigned u = __builtin_bit_cast(unsigned, f);
  unsigned r = (u + 0x7fffu + ((u >> 16) & 1u)) >> 16;   // RNE
  return (short)(unsigned short)r;
}
__device__ __forceinline__ float bf2f(short s){
  return __builtin_bit_cast(float, ((unsigned)(unsigned short)s) << 16);
}

__device__ __forceinline__ f32x4 mfma16(s8v a, s8v b, f32x4 c){
  return __builtin_amdgcn_mfma_f32_16x16x32_bf16(
      __builtin_bit_cast(b8v, a), __builtin_bit_cast(b8v, b), c, 0, 0, 0);
}

__device__ __forceinline__ unsigned cvtpk(float a, float b){
  unsigned w;
  asm("v_cvt_pk_bf16_f32 %0, %1, %2" : "=v"(w) : "v"(a), "v"(b));
  return w;
}

// ---------------- LayerNorm over E=1024 -> bf16 ----------------
__global__ __launch_bounds__(256)
void ln_k(const float* __restrict__ x, const float* __restrict__ g,
          const float* __restrict__ b, short* __restrict__ out)
{
  const int row = blockIdx.x, tid = threadIdx.x;
  const float4 v = ((const float4*)(x + (size_t)row*1024))[tid];
  float s  = v.x+v.y+v.z+v.w;
  float s2 = v.x*v.x+v.y*v.y+v.z*v.z+v.w*v.w;
  #pragma unroll
  for (int off=32; off; off>>=1){ s += __shfl_down(s, off); s2 += __shfl_down(s2, off); }
  __shared__ float red[8];
  const int wave = tid>>6, lane = tid&63;
  if (lane==0){ red[wave]=s; red[4+wave]=s2; }
  __syncthreads();
  s  = red[0]+red[1]+red[2]+red[3];
  s2 = red[4]+red[5]+red[6]+red[7];
  const float mean = s*(1.f/1024.f);
  const float rstd = rsqrtf(s2*(1.f/1024.f) - mean*mean + 1e-5f);
  const float4 gv = ((const float4*)g)[tid];
  const float4 bv = ((const float4*)b)[tid];
  s4v o;
  o[0] = f2bf((v.x-mean)*rstd*gv.x + bv.x);
  o[1] = f2bf((v.y-mean)*rstd*gv.y + bv.y);
  o[2] = f2bf((v.z-mean)*rstd*gv.z + bv.z);
  o[3] = f2bf((v.w-mean)*rstd*gv.w + bv.w);
  *(s4v*)(out + (size_t)row*1024 + tid*4) = o;
}

// ---------------- f32 -> bf16 cast (4 elems/thread) ----------------
__global__ __launch_bounds__(256)
void cast_k(const float* __restrict__ in, short* __restrict__ out)
{
  const int i = blockIdx.x*256 + threadIdx.x;
  const float4 v = ((const float4*)in)[i];
  s4v o; o[0]=f2bf(v.x); o[1]=f2bf(v.y); o[2]=f2bf(v.z); o[3]=f2bf(v.w);
  ((s4v*)out)[i] = o;
}

// ---- mask int -> additive f32 bias (0 / -1.5e9), both masks in one launch ----
__global__ __launch_bounds__(256)
void mkb_k(const int* __restrict__ xm, const int* __restrict__ cm,
           float* __restrict__ mbS, float* __restrict__ mbC)
{
  const int i = blockIdx.x*256 + threadIdx.x;
  mbS[i] = xm[i] ? 0.f : -1.5e9f;
  mbC[i] = cm[i] ? 0.f : -1.5e9f;
}

// ------- transpose+cast: in (E2, D2) f32 -> out (D2, E2) bf16; merged multi-tensor -------
// grid.z selects (tensor, head): z = tensor*NH + h. Up to 6 srcs/dsts.
__global__ __launch_bounds__(256)
void tcast6_k(const float* s0_, const float* s1_, const float* s2_,
              const float* s3_, const float* s4_, const float* s5_,
              short* d0_, short* d1_, short* d2_,
              short* d3_, short* d4_, short* d5_,
              int NH, int E2, int D2)
{
  __shared__ float t[32][33];
  const int z = blockIdx.z;
  const int ti = z / NH, h = z % NH;
  const float* srcs[6] = {s0_,s1_,s2_,s3_,s4_,s5_};
  short*       dsts[6] = {d0_,d1_,d2_,d3_,d4_,d5_};
  const float* ip = srcs[ti] + (size_t)h*E2*D2;
  short*       op = dsts[ti] + (size_t)h*D2*E2;
  const int e0 = blockIdx.x*32, d0 = blockIdx.y*32;
  const int tx = threadIdx.x & 31, ty = threadIdx.x >> 5;
  #pragma unroll
  for (int r = ty; r < 32; r += 8)
    t[r][tx] = ip[(size_t)(e0+r)*D2 + d0 + tx];
  __syncthreads();
  #pragma unroll
  for (int r = ty; r < 32; r += 8)
    op[(size_t)(d0+r)*E2 + e0 + tx] = f2bf(t[tx][r]);
}

// ------- bf16 transpose+PERMUTE: V (b,s,h,d) -> Vp[b*H+h][d][s'] where within each
// 64-block s' = ks*32 + hi*8 + e  <->  s = ks*32 + 16*(e>>2) + 4*hi + (e&3)
__global__ __launch_bounds__(256)
void vtrans_k(const short* __restrict__ V, int ldv, short* __restrict__ Vt, int S, int H)
{
  __shared__ short t[32][34];
  const int bh = blockIdx.z;
  const int b = bh / H, h = bh % H;
  const int s0 = blockIdx.x*32, d0 = blockIdx.y*32;
  const int tx = threadIdx.x & 31, ty = threadIdx.x >> 5;
  const short* ip = V + (size_t)b*S*ldv + h*64;
  #pragma unroll
  for (int r = ty; r < 32; r += 8)
    t[r][tx] = ip[(size_t)(s0+r)*ldv + d0 + tx];
  __syncthreads();
  const int s  = s0 + tx;
  const int ks = (s>>5)&1, bb = (tx>>4)&1, hh = (tx>>2)&3, rr = tx&3;
  const int cp = (s & ~63) + ks*32 + hh*8 + bb*4 + rr;
  short* op = Vt + ((size_t)bh*64 + d0)*S;
  #pragma unroll
  for (int r = ty; r < 32; r += 8)
    op[(size_t)r*S + cp] = t[tx][r];
}

// ---- split-K=4 reduce: out = sum(bf16 partials) + bias + resid (f32) ----
__global__ __launch_bounds__(256)
void red4_k(const short* __restrict__ p, const float* __restrict__ bias,
            const float* __restrict__ resid, float* __restrict__ out)
{
  const int i = blockIdx.x*256 + threadIdx.x;
  float4 o = ((const float4*)resid)[i];
  const float4 bv = ((const float4*)bias)[i & 255];
  o.x += bv.x; o.y += bv.y; o.z += bv.z; o.w += bv.w;
  #pragma unroll
  for (int z=0; z<4; z++){
    const s4v v = ((const s4v*)(p + (size_t)z*4194304))[i];
    o.x += bf2f(v[0]); o.y += bf2f(v[1]); o.z += bf2f(v[2]); o.w += bf2f(v[3]);
  }
  ((float4*)out)[i] = o;
}

// ------- 2-phase bf16 GEMM (narrow-N path). SCQ: 0=none, 2=scale all cols -------
template<int BN, int BIAS, int RELU, int RESID, int WF32, int SCQ>
__global__ __launch_bounds__(256, 2)
void gemm_bt(const short* __restrict__ A, const short* __restrict__ Bt,
             const float* __restrict__ bias, const float* __restrict__ resid,
             short* __restrict__ Cb, float* __restrict__ Cf,
             int M, int N, int K)
{
  __shared__ short lds[3][128*32 + BN*32];
  const int nwg = gridDim.x * gridDim.y;
  int id = blockIdx.y * gridDim.x + blockIdx.x;
  id = (id & 7) * (nwg >> 3) + (id >> 3);
  const int bx = id % gridDim.x, by = id / gridDim.x;
  const int m0 = by*128, n0 = bx*BN;

  const int tid  = threadIdx.x;
  const int wave = tid>>6, lane = tid&63;
  const int lo = lane&15, hi = lane>>4;
  const int wm = wave>>1, wn = wave&1;

  constexpr int NJ = BN/32;
  constexpr int BC = BN>>6;
  f32x4 acc[4][NJ] = {};
  const int NK = K >> 5;

  auto stage = [&](int buf, int kt){
    const short* Ag = A  + (size_t)m0*K + kt*32;
    const short* Bg = Bt + (size_t)n0*K + kt*32;
    #pragma unroll
    for (int c=0;c<2;c++){
      const int q = (wave*2+c)*64 + lane;
      const int r = q>>2, cc = q&3;
      __builtin_amdgcn_global_load_lds(
        (const __attribute__((address_space(1))) void*)(Ag + (size_t)r*K + cc*8),
        (__attribute__((address_space(3))) void*)(&lds[buf][(wave*2+c)*512]),
        16, 0, 0);
    }
    #pragma unroll
    for (int c=0;c<BC;c++){
      const int q = (wave*BC+c)*64 + lane;
      const int r = q>>2, cc = q&3;
      __builtin_amdgcn_global_load_lds(
        (const __attribute__((address_space(1))) void*)(Bg + (size_t)r*K + cc*8),
        (__attribute__((address_space(3))) void*)(&lds[buf][4096 + (wave*BC+c)*512]),
        16, 0, 0);
    }
  };

  stage(0, 0);
  if (NK > 1) stage(1, 1);

  for (int kt=0; kt<NK; kt++){
    if (kt+1 < NK){
      if constexpr (BN==128) asm volatile("s_waitcnt vmcnt(4)" ::: "memory");
      else                   asm volatile("s_waitcnt vmcnt(3)" ::: "memory");
    } else {
      asm volatile("s_waitcnt vmcnt(0)" ::: "memory");
    }
    __builtin_amdgcn_s_barrier();
    __builtin_amdgcn_sched_barrier(0);
    if (kt+2 < NK) stage((kt+2)%3, kt+2);

    const short* la = &lds[kt%3][0];
    const short* lb = &lds[kt%3][4096];
    s8v af[4], bfr[NJ];
    #pragma unroll
    for (int i=0;i<4;i++)
      af[i] = *(const s8v*)(la + (wm*64 + i*16 + lo)*32 + hi*8);
    #pragma unroll
    for (int j=0;j<NJ;j++)
      bfr[j] = *(const s8v*)(lb + (wn*(BN/2) + j*16 + lo)*32 + hi*8);
    #pragma unroll
    for (int i=0;i<4;i++)
      #pragma unroll
      for (int j=0;j<NJ;j++)
        acc[i][j] = mfma16(af[i], bfr[j], acc[i][j]);
  }

  #pragma unroll
  for (int i=0;i<4;i++){
    const int row = m0 + wm*64 + i*16 + hi*4;
    #pragma unroll
    for (int j=0;j<NJ;j++){
      const int col = n0 + wn*(BN/2) + j*16 + lo;
      const float bv = BIAS ? bias[col] : 0.0f;
      #pragma unroll
      for (int r=0;r<4;r++){
        float v = acc[i][j][r] + bv;
        if constexpr (SCQ==2) v *= SC2Q;
        if (RELU) v = fmaxf(v, 0.0f);
        const size_t idx = (size_t)(row + r)*N + col;
        if (RESID) v += resid[idx];
        if (WF32) Cf[idx] = v; else Cb[idx] = f2bf(v);
      }
    }
  }
}

// ------- m201-geometry bf16 GEMM: 256x256, BK=64, 8 waves, per-wave 128x64. -------
template<int BIAS, int RELU, int RESID, int WF32, int SCQ>
__global__ __launch_bounds__(512, 1)
void gemm256(const short* __restrict__ A, int lda,
             const short* __restrict__ Bt, int ldb,
             const float* __restrict__ bias, const float* __restrict__ resid,
             short* __restrict__ Cb, float* __restrict__ Cf,
             int M, int N, int K)
{
  __shared__ short lds[2][32768];
  const int nwg = gridDim.x * gridDim.y;
  int id = blockIdx.y * gridDim.x + blockIdx.x;
  id = (id & 7) * (nwg >> 3) + (id >> 3);
  const int bx = id % gridDim.x, by = id / gridDim.x;
  const int m0 = by*256, n0 = bx*256;
  A  += (size_t)blockIdx.z * K;
  Bt += (size_t)blockIdx.z * K;
  const size_t cofs = (size_t)blockIdx.z * M * N;

  const int tid = threadIdx.x;
  const int lane = tid&63, wave = tid>>6;
  const int lo = lane&15, hi = lane>>4;
  const int wr = wave>>2, wc = wave&3;

  f32x4 acc[8][4] = {};
  const int NT = K >> 6;

  auto stageA = [&](int buf, int kt, int part){
    const short* Ag = A + (size_t)m0*lda + kt*64;
    const int q = part*512 + tid;
    const int r = q>>3, c = q&7;
    __builtin_amdgcn_global_load_lds(
      (const __attribute__((address_space(1))) void*)(Ag + (size_t)r*lda + ((c^(r&7))*8)),
      (__attribute__((address_space(3))) void*)(&lds[buf][q*8]), 16, 0, 0);
  };
  auto stageB = [&](int buf, int kt, int part){
    const short* Bg = Bt + (size_t)n0*ldb + kt*64;
    const int q = part*512 + tid;
    const int r = q>>3, c = q&7;
    __builtin_amdgcn_global_load_lds(
      (const __attribute__((address_space(1))) void*)(Bg + (size_t)r*ldb + ((c^(r&7))*8)),
      (__attribute__((address_space(3))) void*)(&lds[buf][16384 + q*8]), 16, 0, 0);
  };

  #pragma unroll
  for (int p=0;p<4;p++){ stageA(0,0,p); stageB(0,0,p); }
  __syncthreads();

  for (int t=0; t<NT; t++){
    const int cur = t&1;
    const short* la = &lds[cur][0];
    const short* lb = &lds[cur][16384];
    const bool pf = (t+1 < NT);
    #pragma unroll
    for (int ks=0; ks<2; ks++){
      s8v bf[4];
      #pragma unroll
      for (int j=0;j<4;j++){
        const int r = wc*64 + j*16 + lo;
        bf[j] = *(const s8v*)(lb + r*64 + (((ks*4+hi)^(r&7))*8));
      }
      #pragma unroll
      for (int mh=0; mh<2; mh++){
        s8v af[4];
        #pragma unroll
        for (int i=0;i<4;i++){
          const int r = wr*128 + mh*64 + i*16 + lo;
          af[i] = *(const s8v*)(la + r*64 + (((ks*4+hi)^(r&7))*8));
        }
        if (pf && ks==0){
          stageA(cur^1, t+1, mh*2);   stageB(cur^1, t+1, mh*2);
          stageA(cur^1, t+1, mh*2+1); stageB(cur^1, t+1, mh*2+1);
        }
        __builtin_amdgcn_s_setprio(1);
        #pragma unroll
        for (int i=0;i<4;i++)
          #pragma unroll
          for (int j=0;j<4;j++)
            acc[mh*4+i][j] = mfma16(af[i], bf[j], acc[mh*4+i][j]);
        __builtin_amdgcn_s_setprio(0);
      }
    }
    __syncthreads();
  }

  #pragma unroll
  for (int I=0;I<8;I++){
    const int row = m0 + wr*128 + I*16 + hi*4;
    #pragma unroll
    for (int j=0;j<4;j++){
      const int col = n0 + wc*64 + j*16 + lo;
      const float bv = BIAS ? bias[col] : 0.0f;
      #pragma unroll
      for (int r=0;r<4;r++){
        float v = acc[I][j][r] + bv;
        if constexpr (SCQ==1) { if (col < 1024) v *= SC2Q; }
        if (RELU) v = fmaxf(v, 0.0f);
        const size_t idx = cofs + (size_t)(row + r)*N + col;
        if (RESID) v += resid[idx];
        if (WF32) Cf[idx] = v; else Cb[idx] = f2bf(v);
      }
    }
  }
}

// ---- flash attention v7 (R11 proven): hoisted addressing, lrow-via-ones-MFMA,
// max3 trees, LDS K/V (2-buffer, swizzled), swapped QK^T in-reg softmax,
// pre-scaled Q, additive mask bias, defer-max, b128 V frags (permuted Vp).
template<int CAUSAL>
__global__ __launch_bounds__(256, 4)
void attn_k(const short* __restrict__ Q, int ldq,
            const short* __restrict__ K, int ldk,
            const short* __restrict__ Vt, int ldvt,   // Vp[b*H+h][d][s'] permuted
            const float* __restrict__ mbias,
            short* __restrict__ O, int ldo,
            int H, int Tq, int Sk)
{
  __shared__ short kls[2][4096];
  __shared__ short vls[2][4096];
  const int bh = blockIdx.x;
  const int b = bh / H, h = bh % H;
  const int tid = threadIdx.x;
  const int wave = tid>>6, lane = tid&63;
  const int lo = lane&15, hi = lane>>4;
  const int t0 = blockIdx.y*64 + wave*16;

  const short* Qb  = Q + (size_t)(b*Tq)*ldq + h*64;
  const short* Kb  = K + (size_t)(b*Sk)*ldk + h*64;
  const short* Vtb = Vt + (size_t)bh*64*ldvt;

  const short* qp = Qb + (size_t)(t0+lo)*ldq + hi*8;
  const s8v qa0 = *(const s8v*)(qp);
  const s8v qa1 = *(const s8v*)(qp + 32);

  float mrow = -INFINITY;
  f32x4 oacc[4] = {};
  f32x4 oaccL = {};                           // row-sum via ones-MFMA
  const int trow = t0 + lo;
  const int nblk = CAUSAL ? (blockIdx.y + 1) : (Sk>>6);
  const int x8 = lo & 7;

  const s8v onesv = {(short)0x3F80,(short)0x3F80,(short)0x3F80,(short)0x3F80,
                     (short)0x3F80,(short)0x3F80,(short)0x3F80,(short)0x3F80};

  // ---- staging source pointers (incremented each stage; no recompute) ----
  const int q0 = tid, q1 = 256 + tid;
  const int r0 = q0>>3, cs0 = ((q0&7) ^ (r0&7))*8;
  const int r1 = q1>>3, cs1 = ((q1&7) ^ (r1&7))*8;
  const short* kS0 = Kb + (size_t)r0*ldk + cs0;
  const short* kS1 = Kb + (size_t)r1*ldk + cs1;
  const short* vS0 = Vtb + (size_t)r0*ldvt + cs0;
  const short* vS1 = Vtb + (size_t)r1*ldvt + cs1;
  const size_t kAdv = (size_t)64*ldk;

  auto stage = [&](int buf){
    __builtin_amdgcn_global_load_lds(
      (const __attribute__((address_space(1))) void*)kS0,
      (__attribute__((address_space(3))) void*)(&kls[buf][wave*512]), 16, 0, 0);
    __builtin_amdgcn_global_load_lds(
      (const __attribute__((address_space(1))) void*)kS1,
      (__attribute__((address_space(3))) void*)(&kls[buf][2048 + wave*512]), 16, 0, 0);
    __builtin_amdgcn_global_load_lds(
      (const __attribute__((address_space(1))) void*)vS0,
      (__attribute__((address_space(3))) void*)(&vls[buf][wave*512]), 16, 0, 0);
    __builtin_amdgcn_global_load_lds(
      (const __attribute__((address_space(1))) void*)vS1,
      (__attribute__((address_space(3))) void*)(&vls[buf][2048 + wave*512]), 16, 0, 0);
    kS0 += kAdv; kS1 += kAdv; vS0 += 64; vS1 += 64;
  };

  // ---- hoisted LDS read bases (byte offsets; toggle by XOR 8192) ----
  const char* klsB = (const char*)kls;
  const char* vlsB = (const char*)vls;
  const int A0 = lo*128 + ((hi     ^ x8)*16);
  const int A1 = lo*128 + (((4+hi) ^ x8)*16);
  int curB = 0;

  // ---- mask pointer (advance 256B/iter) ----
  const char* mbp = (const char*)(mbias + (size_t)b*Sk) + hi*16;

  stage(0);
  for (int it=0; it<nblk; it++){
    __syncthreads();
    if (it+1 < nblk) stage((it+1)&1);

    // ---- K fragments (swapped A-operand): 2 base addrs + imm offsets ----
    const char* ka0 = klsB + curB + A0;
    const char* ka1 = klsB + curB + A1;
    s8v kf[4][2];
    #pragma unroll
    for (int g=0; g<4; g++){
      kf[g][0] = *(const s8v*)(ka0 + g*2048);
      kf[g][1] = *(const s8v*)(ka1 + g*2048);
    }

    f32x4 sg[4] = {};
    __builtin_amdgcn_s_setprio(1);
    #pragma unroll
    for (int g=0; g<4; g++){
      sg[g] = mfma16(kf[g][0], qa0, sg[g]);
      sg[g] = mfma16(kf[g][1], qa1, sg[g]);
    }
    __builtin_amdgcn_s_setprio(0);

    // ---- additive mask bias ----
    float p[4][4];
    #pragma unroll
    for (int g=0; g<4; g++){
      const f32x4 mv = *(const f32x4*)(mbp + g*64);
      #pragma unroll
      for (int r=0; r<4; r++)
        p[g][r] = sg[g][r] + mv[r];
    }
    mbp += 256;
    if (CAUSAL && it == nblk-1){
      const int s0 = it*64;
      #pragma unroll
      for (int g=0; g<4; g++)
        #pragma unroll
        for (int r=0; r<4; r++){
          const int sidx = s0 + g*16 + 4*hi + r;
          if (sidx > trow) p[g][r] = -1.5e9f;
        }
    }

    // ---- row max via max3 chains + 2 cross-lane rounds ----
    float bmax;
    {
      const float m0_ = fmaxf(fmaxf(p[0][0],p[0][1]),p[0][2]);
      const float m1_ = fmaxf(fmaxf(p[0][3],p[1][0]),p[1][1]);
      const float m2_ = fmaxf(fmaxf(p[1][2],p[1][3]),p[2][0]);
      const float m3_ = fmaxf(fmaxf(p[2][1],p[2][2]),p[2][3]);
      const float m4_ = fmaxf(fmaxf(p[3][0],p[3][1]),p[3][2]);
      bmax = fmaxf(fmaxf(fmaxf(m0_,m1_),m2_), fmaxf(fmaxf(m3_,m4_),p[3][3]));
    }
    bmax = fmaxf(bmax, __shfl_xor(bmax, 16));
    bmax = fmaxf(bmax, __shfl_xor(bmax, 32));

    // ---- T13 defer-max rescale (includes oaccL) ----
    if (!__all(bmax <= mrow + 8.0f)){
      const float mn  = fmaxf(mrow, bmax);
      const float fac = exp2f(mrow - mn);
      mrow = mn;
      #pragma unroll
      for (int f=0; f<4; f++)
        #pragma unroll
        for (int r=0; r<4; r++)
          oacc[f][r] *= fac;
      #pragma unroll
      for (int r=0; r<4; r++) oaccL[r] *= fac;
    }

    // ---- exp2 ----
    #pragma unroll
    for (int g=0; g<4; g++)
      #pragma unroll
      for (int r=0; r<4; r++)
        p[g][r] = exp2f(p[g][r] - mrow);

    // ---- pack P -> bf16 B-operand ----
    u32x4 pw0, pw1;
    pw0[0] = cvtpk(p[0][0], p[0][1]);
    pw0[1] = cvtpk(p[0][2], p[0][3]);
    pw0[2] = cvtpk(p[1][0], p[1][1]);
    pw0[3] = cvtpk(p[1][2], p[1][3]);
    pw1[0] = cvtpk(p[2][0], p[2][1]);
    pw1[1] = cvtpk(p[2][2], p[2][3]);
    pw1[2] = cvtpk(p[3][0], p[3][1]);
    pw1[3] = cvtpk(p[3][2], p[3][3]);
    const s8v pb0 = __builtin_bit_cast(s8v, pw0);
    const s8v pb1 = __builtin_bit_cast(s8v, pw1);

    // ---- V fragments + PV; lrow accumulated by ones-MFMA ----
    const char* va0 = vlsB + curB + A0;
    const char* va1 = vlsB + curB + A1;
    __builtin_amdgcn_s_setprio(1);
    #pragma unroll
    for (int f=0; f<4; f++){
      const s8v av0 = *(const s8v*)(va0 + f*2048);
      const s8v av1 = *(const s8v*)(va1 + f*2048);
      oacc[f] = mfma16(av0, pb0, oacc[f]);
      oacc[f] = mfma16(av1, pb1, oacc[f]);
    }
    oaccL = mfma16(onesv, pb0, oaccL);
    oaccL = mfma16(onesv, pb1, oaccL);
    __builtin_amdgcn_s_setprio(0);
    curB ^= 8192;
  }

  const float inv = 1.0f / oaccL[0];
  short* Ob = O + (size_t)(b*Tq)*ldo + h*64 + (size_t)(t0+lo)*ldo + 4*hi;
  #pragma unroll
  for (int f=0; f<4; f++){
    s4v o;
    #pragma unroll
    for (int r=0; r<4; r++) o[r] = f2bf(oacc[f][r]*inv);
    *(s4v*)(Ob + f*16) = o;
  }
}

// =============================== host ===============================
extern "C" void kernel_launch(void* const* d_in, const int* in_sizes, int n_in,
                              void* d_out, int out_size, void* d_ws, size_t ws_size,
                              hipStream_t stream)
{
  (void)in_sizes; (void)n_in; (void)out_size; (void)ws_size;
  const float* x    = (const float*)d_in[0];
  const int*   xm   = (const int*)  d_in[1];
  const float* ca   = (const float*)d_in[2];
  const int*   cam  = (const int*)  d_in[3];
  const float* Wq_s = (const float*)d_in[4];
  const float* Wk_s = (const float*)d_in[5];
  const float* Wv_s = (const float*)d_in[6];
  const float* Wo_s = (const float*)d_in[7];
  const float* bo_s = (const float*)d_in[8];
  const float* Wq_c = (const float*)d_in[9];
  const float* Wk_c = (const float*)d_in[10];
  const float* Wv_c = (const float*)d_in[11];
  const float* Wo_c = (const float*)d_in[12];
  const float* bo_c = (const float*)d_in[13];
  const float* ln1g = (const float*)d_in[14];
  const float* ln1b = (const float*)d_in[15];
  const float* ln2g = (const float*)d_in[16];
  const float* ln2b = (const float*)d_in[17];
  const float* ln3g = (const float*)d_in[18];
  const float* ln3b = (const float*)d_in[19];
  const float* W1   = (const float*)d_in[20];
  const float* b1   = (const float*)d_in[21];
  const float* W2   = (const float*)d_in[22];
  const float* b2   = (const float*)d_in[23];
  float* out = (float*)d_out;

  char* ws = (char*)d_ws;
  size_t off = 0;
  auto alloc = [&](size_t bytes)->void*{
    void* p = ws + off; off += (bytes + 255) & ~(size_t)255; return p; };

  short* w_qkv_s = (short*)alloc((size_t)3072*1024*2);
  short* w_o_s   = (short*)alloc((size_t)1024*1024*2);
  short* w_q_c   = (short*)alloc((size_t)1024*1024*2);
  short* w_kv_c  = (short*)alloc((size_t)2048*1024*2);
  short* w_o_c   = (short*)alloc((size_t)1024*1024*2);
  short* w_1     = (short*)alloc((size_t)4096*1024*2);
  short* w_2     = (short*)alloc((size_t)1024*4096*2);
  short* xn      = (short*)alloc((size_t)4096*1024*2);
  short* cab     = (short*)alloc((size_t)4096*1024*2);
  short* qkv     = (short*)alloc((size_t)4096*3072*2);
  short* attno   = (short*)alloc((size_t)4096*1024*2);
  float* xres    = (float*)alloc((size_t)4096*1024*4);
  short* hffn    = (short*)alloc((size_t)4096*4096*2);
  float* pA      = (float*)alloc((size_t)4096*1024*4);
  float* pB      = (float*)alloc((size_t)4096*1024*4);
  float* mbS     = (float*)alloc((size_t)4096*4);
  float* mbC     = (float*)alloc((size_t)4096*4);
  short* pP      = (short*)pA;
  short* kvbuf   = qkv + (size_t)4096*1024;
  short* vt_s    = hffn;
  short* vt_c    = hffn + (size_t)4*1024*1024;
  (void)pB;

  // merged head-weight repacks: 6 tensors x 16 heads (E2=1024, D2=64)
  tcast6_k<<<dim3(32,2,96),256,0,stream>>>(
      Wq_s, Wk_s, Wv_s, Wq_c, Wk_c, Wv_c,
      w_qkv_s, w_qkv_s+1024*1024, w_qkv_s+2048*1024,
      w_q_c, w_kv_c, w_kv_c+1024*1024, 16, 1024, 64);
  // merged square repacks: Wo_s, Wo_c (E2=D2=1024, 1 "head" each -> z in {0,1})
  tcast6_k<<<dim3(32,32,2),256,0,stream>>>(
      Wo_s, Wo_c, nullptr, nullptr, nullptr, nullptr,
      w_o_s, w_o_c, nullptr, nullptr, nullptr, nullptr, 1, 1024, 1024);
  // FFN weights (different shapes -> separate)
  tcast6_k<<<dim3(32,128,1),256,0,stream>>>(
      W1, nullptr, nullptr, nullptr, nullptr, nullptr,
      w_1, nullptr, nullptr, nullptr, nullptr, nullptr, 1, 1024, 4096);
  tcast6_k<<<dim3(128,32,1),256,0,stream>>>(
      W2, nullptr, nullptr, nullptr, nullptr, nullptr,
      w_2, nullptr, nullptr, nullptr, nullptr, nullptr, 1, 4096, 1024);
  cast_k<<<4096,256,0,stream>>>(ca, cab);
  mkb_k<<<16,256,0,stream>>>(xm, cam, mbS, mbC);

  // --- self attention ---
  ln_k<<<4096,256,0,stream>>>(x, ln1g, ln1b, xn);
  gemm256<0,0,0,0,1><<<dim3(12,16),512,0,stream>>>(xn, 1024, w_qkv_s, 1024,
                                                   nullptr, nullptr, qkv, nullptr,
                                                   4096, 3072, 1024);
  vtrans_k<<<dim3(32,2,64),256,0,stream>>>(qkv+2048, 3072, vt_s, 1024, 16);
  attn_k<1><<<dim3(64,16),256,0,stream>>>(qkv, 3072, qkv+1024, 3072, vt_s, 1024,
                                          mbS, attno, 1024, 16, 1024, 1024);
  gemm_bt<64,1,0,1,1,0><<<dim3(16,32),256,0,stream>>>(attno, w_o_s, bo_s, x,
                                                      nullptr, xres, 4096, 1024, 1024);

  // --- cross attention (K,V from raw ca) ---
  ln_k<<<4096,256,0,stream>>>(xres, ln2g, ln2b, xn);
  gemm_bt<64,0,0,0,0,2><<<dim3(16,32),256,0,stream>>>(xn, w_q_c, nullptr, nullptr,
                                                      qkv, nullptr, 4096, 1024, 1024);
  gemm256<0,0,0,0,0><<<dim3(8,16),512,0,stream>>>(cab, 1024, w_kv_c, 1024,
                                                  nullptr, nullptr, kvbuf, nullptr,
                                                  4096, 2048, 1024);
  vtrans_k<<<dim3(32,2,64),256,0,stream>>>(kvbuf+1024, 2048, vt_c, 1024, 16);
  attn_k<0><<<dim3(64,16),256,0,stream>>>(qkv, 1024, kvbuf, 2048, vt_c, 1024,
                                          mbC, attno, 1024, 16, 1024, 1024);
  gemm_bt<64,1,0,1,1,0><<<dim3(16,32),256,0,stream>>>(attno, w_o_c, bo_c, xres,
                                                      nullptr, xres, 4096, 1024, 1024);

  // --- FFN ---
  ln_k<<<4096,256,0,stream>>>(xres, ln3g, ln3b, xn);
  gemm256<1,1,0,0,0><<<dim3(16,16),512,0,stream>>>(xn, 1024, w_1, 1024,
                                                   b1, nullptr, hffn, nullptr,
                                                   4096, 4096, 1024);
  gemm256<0,0,0,0,0><<<dim3(4,16,4),512,0,stream>>>(hffn, 4096, w_2, 4096,
                                                    nullptr, nullptr, pP, nullptr,
                                                    4096, 1024, 1024);
  red4_k<<<4096,256,0,stream>>>(pP, b2, xres, out);
}